// Round 1
// 1402.449 us; speedup vs baseline: 1.0413x; 1.0413x over previous
//
#include <hip/hip_runtime.h>

// ---------------- problem constants ----------------
#define DIMC   512
#define HWIN   1681   // 41*41
#define WIN_   41
#define HWOUT  400    // 20*20
#define COUT   256    // 128 qk-proj + 128 v-proj
#define KD     4608   // 512*9
#define NIMG   208    // 8 query + 200 supports
#define NPAIR  40     // 8 * 5
#define NJ     2000   // 5 * 400
#define MTOT   83200  // 208 * 400 flattened conv-GEMM rows

typedef __bf16 bf16;
typedef __bf16 bf16x4 __attribute__((ext_vector_type(4)));
typedef __bf16 bf16x8 __attribute__((ext_vector_type(8)));
typedef float  f32x16 __attribute__((ext_vector_type(16)));

// ---------------- workspace layout (bytes) ----------------
// Wb  : bf16 [256][4608]       (combined conv weights, k = t*512+c, row-major n)
// F   : bf16 [208][400][256]   (conv output, channel-last)
// VT  : bf16 [40][128][2000]   (V transposed per (b,k))
// dist: f32  [40]
// R   : bf16 [208][1681][512]  (channel-last input) -- aliased by S f32 [40][400][2000]
#define OFF_WB   0ull
#define OFF_F    2359296ull
#define OFF_VT   44957696ull
#define OFF_DIST 65437696ull
#define OFF_R    65437952ull
#define WS_NEED  (OFF_R + 358039552ull)

__device__ __forceinline__ void gl2lds16(const void* g, void* l) {
  __builtin_amdgcn_global_load_lds((const __attribute__((address_space(1))) unsigned int*)g,
                                   (__attribute__((address_space(3))) unsigned int*)l,
                                   16, 0, 0);
}

// ======================= K1: combine weights =======================
// C[n][p] = sum_o W[n][o] * w_ms[o][p], p = c*9+t ; store Wb[n][t*512+c] (bf16)
__global__ __launch_bounds__(256) void k_wcomb(const float* __restrict__ wqk,
                                               const float* __restrict__ wv,
                                               const float* __restrict__ wms,
                                               bf16* __restrict__ Wb) {
  __shared__ float As[64][33];
  __shared__ float Bs[32][65];
  const int tid = threadIdx.x;
  const int bp = blockIdx.x, bn = blockIdx.y;
  const int tx = tid & 15, ty = tid >> 4;
  float acc[4][4] = {};
  for (int ko = 0; ko < 512; ko += 32) {
#pragma unroll
    for (int i = 0; i < 8; ++i) {
      int idx = tid + i * 256;
      int r = idx >> 5, c = idx & 31;
      int row = bn * 64 + r;
      As[r][c] = (row < 128) ? wqk[row * 512 + ko + c] : wv[(row - 128) * 512 + ko + c];
    }
#pragma unroll
    for (int i = 0; i < 8; ++i) {
      int idx = tid + i * 256;
      int r = idx >> 6, c = idx & 63;
      Bs[r][c] = wms[(size_t)(ko + r) * KD + bp * 64 + c];
    }
    __syncthreads();
#pragma unroll
    for (int kk = 0; kk < 32; ++kk) {
      float av[4], bv[4];
#pragma unroll
      for (int i = 0; i < 4; ++i) av[i] = As[ty * 4 + i][kk];
#pragma unroll
      for (int j = 0; j < 4; ++j) bv[j] = Bs[kk][tx * 4 + j];
#pragma unroll
      for (int i = 0; i < 4; ++i)
#pragma unroll
        for (int j = 0; j < 4; ++j) acc[i][j] += av[i] * bv[j];
    }
    __syncthreads();
  }
#pragma unroll
  for (int i = 0; i < 4; ++i)
#pragma unroll
    for (int j = 0; j < 4; ++j) {
      int n = bn * 64 + ty * 4 + i;
      int p = bp * 64 + tx * 4 + j;
      int c = p / 9, t = p - c * 9;
      Wb[(size_t)n * KD + t * DIMC + c] = (bf16)acc[i][j];
    }
}

// ======================= K2: repack input to channel-last bf16 =======================
__global__ __launch_bounds__(256) void k_repack(const float* __restrict__ q,
                                                const float* __restrict__ s,
                                                bf16* __restrict__ R) {
  __shared__ bf16 Ls[64][65];   // [channel][x]
  const int tid = threadIdx.x;
  const int bx = blockIdx.x, by = blockIdx.y, img = blockIdx.z;
  const float* src = (img < 8) ? (q + (size_t)img * DIMC * HWIN)
                               : (s + (size_t)(img - 8) * DIMC * HWIN);
  const int x0 = bx * 64, c0 = by * 64;
#pragma unroll
  for (int i = 0; i < 16; ++i) {
    int idx = i * 256 + tid;
    int r = idx >> 6, cx = idx & 63;
    int xx = x0 + cx;
    if (xx < HWIN) Ls[r][cx] = (bf16)src[(size_t)(c0 + r) * HWIN + xx];
  }
  __syncthreads();
#pragma unroll
  for (int i = 0; i < 4; ++i) {
    int idx = i * 256 + tid;
    int prow = idx >> 4, cq = idx & 15;
    int xx = x0 + prow;
    if (xx < HWIN) {
      bf16x4 v;
      v[0] = Ls[cq * 4 + 0][prow];
      v[1] = Ls[cq * 4 + 1][prow];
      v[2] = Ls[cq * 4 + 2][prow];
      v[3] = Ls[cq * 4 + 3][prow];
      *(bf16x4*)(R + ((size_t)img * HWIN + xx) * DIMC + c0 + cq * 4) = v;
    }
  }
}

// ======================= K3: conv as ONE flat implicit GEMM (bf16 MFMA) =======================
// M = 208*400 = 83200 rows flattened across images (650 blocks x 128 rows, zero padding),
// N = 256 out channels, K = 9 taps * 512 c, BK = 64.
// Per wave: 128x64 output = 4m x 2n 32x32 tiles -> 24 ds_read_b128 : 32 MFMA per K-step.
__global__ __launch_bounds__(256, 2) void k_conv(const bf16* __restrict__ R,
                                                 const bf16* __restrict__ Wb,
                                                 bf16* __restrict__ F) {
  __shared__ __align__(16) bf16 As[128 * 64];   // rows 128B, 8 chunks, XOR(m&7) swizzle
  __shared__ __align__(16) bf16 Bs[256 * 64];
  const int tid = threadIdx.x;
  const int lane = tid & 63, wave = tid >> 6;
  const int blk = blockIdx.x;

  // A: 4 gl2lds issues per wave; rows m = (wave*4+i)*8 + (lane>>3), all valid (no padding)
  unsigned aPix[4];
#pragma unroll
  for (int i = 0; i < 4; ++i) {
    int issue = wave * 4 + i;
    int m = issue * 8 + (lane >> 3);
    int g = (lane & 7) ^ (m & 7);
    int gm = blk * 128 + m;              // global output row 0..83199
    int img = gm / 400, p = gm - img * 400;
    int oy = p / 20, ox = p - oy * 20;
    aPix[i] = (unsigned)((img * HWIN + (2 * oy) * WIN_ + 2 * ox) * DIMC) + (unsigned)g * 8;
  }
  // B: 8 issues per wave cover all 256 Wb rows
  unsigned bOfs[8];
#pragma unroll
  for (int i = 0; i < 8; ++i) {
    int ib = wave * 8 + i;
    int n = ib * 8 + (lane >> 3);
    int g = (lane & 7) ^ (n & 7);
    bOfs[i] = (unsigned)n * KD + (unsigned)g * 8;
  }

  f32x16 acc[4][2];
#pragma unroll
  for (int mi = 0; mi < 4; ++mi)
#pragma unroll
    for (int ni = 0; ni < 2; ++ni)
#pragma unroll
      for (int r = 0; r < 16; ++r) acc[mi][ni][r] = 0.f;

  for (int t = 0; t < 9; ++t) {
    const int dy = t / 3, dx = t - dy * 3;
    const unsigned tapoff = (unsigned)((dy * WIN_ + dx) * DIMC);
    for (int cc = 0; cc < 8; ++cc) {
      const unsigned c0 = (unsigned)(cc * 64);
#pragma unroll
      for (int i = 0; i < 4; ++i) {
        int issue = wave * 4 + i;
        gl2lds16(R + aPix[i] + tapoff + c0, (char*)As + issue * 1024);
      }
#pragma unroll
      for (int i = 0; i < 8; ++i) {
        int ib = wave * 8 + i;
        gl2lds16(Wb + bOfs[i] + (unsigned)(t * DIMC) + c0, (char*)Bs + ib * 1024);
      }
      __syncthreads();
      const int mr = lane & 31;
#pragma unroll
      for (int kq = 0; kq < 4; ++kq) {
        const int chunk = kq * 2 + (lane >> 5);
        bf16x8 a[4], b[2];
#pragma unroll
        for (int mi = 0; mi < 4; ++mi) {
          int m = mi * 32 + mr;
          int slot = chunk ^ (m & 7);
          a[mi] = *(const bf16x8*)((const char*)As + m * 128 + slot * 16);
        }
#pragma unroll
        for (int ni = 0; ni < 2; ++ni) {
          int n = wave * 64 + ni * 32 + mr;
          int slot = chunk ^ (n & 7);
          b[ni] = *(const bf16x8*)((const char*)Bs + n * 128 + slot * 16);
        }
#pragma unroll
        for (int mi = 0; mi < 4; ++mi)
#pragma unroll
          for (int ni = 0; ni < 2; ++ni)
            acc[mi][ni] = __builtin_amdgcn_mfma_f32_32x32x16_bf16(a[mi], b[ni], acc[mi][ni], 0, 0, 0);
      }
      __syncthreads();
    }
  }
  const int col = lane & 31, hi = lane >> 5;
#pragma unroll
  for (int mi = 0; mi < 4; ++mi)
#pragma unroll
    for (int ni = 0; ni < 2; ++ni)
#pragma unroll
      for (int r = 0; r < 16; ++r) {
        int row = (r & 3) + 8 * (r >> 2) + 4 * hi;
        int gm = blk * 128 + mi * 32 + row;
        int ch = wave * 64 + ni * 32 + col;
        F[(size_t)gm * COUT + ch] = (bf16)acc[mi][ni][r];
      }
}

// ======================= K4: sim = Q K^T * scale =======================
__global__ __launch_bounds__(256) void k_sim(const bf16* __restrict__ F,
                                             float* __restrict__ S) {
  __shared__ __align__(16) bf16 As[96 * 64];
  __shared__ __align__(16) bf16 Bs[256 * 64];
  const int tid = threadIdx.x, lane = tid & 63, wave = tid >> 6;
  const int mt = blockIdx.x, nt = blockIdx.y, pair = blockIdx.z;
  const int b = pair / 5, kidx = pair - b * 5;
  const int simg = 8 + b * 25 + kidx * 5;

  unsigned aBase[3];
#pragma unroll
  for (int i = 0; i < 3; ++i) {
    int issue = wave * 3 + i;
    int m = issue * 8 + (lane >> 3);
    int g = (lane & 7) ^ (m & 7);
    int pm = mt * 96 + m;
    if (pm >= HWOUT) pm = 0;
    aBase[i] = (unsigned)((b * HWOUT + pm) * COUT) + (unsigned)g * 8;
  }
  unsigned bBase[8];
#pragma unroll
  for (int i = 0; i < 8; ++i) {
    int ib = wave * 8 + i;
    int r = ib * 8 + (lane >> 3);
    int g = (lane & 7) ^ (r & 7);
    int jj = nt * 256 + r;
    if (jj >= NJ) jj = 0;
    int nimg = jj / HWOUT, ip = jj - nimg * HWOUT;
    bBase[i] = (unsigned)(((simg + nimg) * HWOUT + ip) * COUT) + (unsigned)g * 8;
  }

  f32x16 acc[3][2];
#pragma unroll
  for (int mi = 0; mi < 3; ++mi)
#pragma unroll
    for (int ni = 0; ni < 2; ++ni)
#pragma unroll
      for (int r = 0; r < 16; ++r) acc[mi][ni][r] = 0.f;

  for (int ks = 0; ks < 2; ++ks) {
    const int c0 = ks * 64;
#pragma unroll
    for (int i = 0; i < 3; ++i)
      gl2lds16(F + aBase[i] + c0, (char*)As + (wave * 3 + i) * 1024);
#pragma unroll
    for (int i = 0; i < 8; ++i)
      gl2lds16(F + bBase[i] + c0, (char*)Bs + (wave * 8 + i) * 1024);
    __syncthreads();
    const int mr = lane & 31;
#pragma unroll
    for (int kq = 0; kq < 4; ++kq) {
      const int chunk = kq * 2 + (lane >> 5);
      bf16x8 a[3], b[2];
#pragma unroll
      for (int mi = 0; mi < 3; ++mi) {
        int m = mi * 32 + mr;
        int slot = chunk ^ (m & 7);
        a[mi] = *(const bf16x8*)((const char*)As + m * 128 + slot * 16);
      }
#pragma unroll
      for (int ni = 0; ni < 2; ++ni) {
        int n = wave * 64 + ni * 32 + mr;
        int slot = chunk ^ (n & 7);
        b[ni] = *(const bf16x8*)((const char*)Bs + n * 128 + slot * 16);
      }
#pragma unroll
      for (int mi = 0; mi < 3; ++mi)
#pragma unroll
        for (int ni = 0; ni < 2; ++ni)
          acc[mi][ni] = __builtin_amdgcn_mfma_f32_32x32x16_bf16(a[mi], b[ni], acc[mi][ni], 0, 0, 0);
    }
    __syncthreads();
  }
  const float scale = 0.08838834764831845f;  // 128^-0.5
  const int col = lane & 31, hi = lane >> 5;
#pragma unroll
  for (int mi = 0; mi < 3; ++mi)
#pragma unroll
    for (int ni = 0; ni < 2; ++ni)
#pragma unroll
      for (int r = 0; r < 16; ++r) {
        int row = (r & 3) + 8 * (r >> 2) + 4 * hi;
        int pix = mt * 96 + mi * 32 + row;
        int j = nt * 256 + wave * 64 + ni * 32 + col;
        if (pix < HWOUT && j < NJ)
          S[((size_t)pair * HWOUT + pix) * NJ + j] = acc[mi][ni][r] * scale;
      }
}

// ======================= K5: softmax rows (in-place, fp32 -> bf16) =======================
__global__ __launch_bounds__(256) void k_softmax(float* __restrict__ S) {
  const int row = blockIdx.x;
  const int tid = threadIdx.x;
  const int lane = tid & 63, wave = tid >> 6;
  float* rp = S + (size_t)row * NJ;
  float v[8];
  float mx = -1e30f;
#pragma unroll
  for (int i = 0; i < 8; ++i) {
    int idx = tid + i * 256;
    v[i] = (idx < NJ) ? rp[idx] : -1e30f;
    mx = fmaxf(mx, v[i]);
  }
  for (int off = 32; off > 0; off >>= 1) mx = fmaxf(mx, __shfl_xor(mx, off));
  __shared__ float sred[4];
  if (lane == 0) sred[wave] = mx;
  __syncthreads();
  mx = fmaxf(fmaxf(sred[0], sred[1]), fmaxf(sred[2], sred[3]));
  __syncthreads();
  float sum = 0.f;
#pragma unroll
  for (int i = 0; i < 8; ++i) {
    v[i] = __expf(v[i] - mx);
    sum += v[i];
  }
  for (int off = 32; off > 0; off >>= 1) sum += __shfl_xor(sum, off);
  if (lane == 0) sred[wave] = sum;
  __syncthreads();
  sum = sred[0] + sred[1] + sred[2] + sred[3];
  const float inv = 1.0f / sum;
  bf16* op = (bf16*)rp;
#pragma unroll
  for (int i = 0; i < 8; ++i) {
    int idx = tid + i * 256;
    if (idx < NJ) op[idx] = (bf16)(v[i] * inv);
  }
}

// ======================= K5b: build VT[pair][c][j] =======================
__global__ __launch_bounds__(256) void k_vt(const bf16* __restrict__ F,
                                            bf16* __restrict__ VT) {
  __shared__ bf16 Ls[64][132];  // [ip-local][c]
  const int tid = threadIdx.x;
  const int pt = blockIdx.x, n = blockIdx.y, pair = blockIdx.z;
  const int b = pair / 5, kidx = pair - b * 5;
  const int img = 8 + b * 25 + kidx * 5 + n;
#pragma unroll
  for (int i = 0; i < 8; ++i) {
    int idx = i * 256 + tid;
    int r = idx >> 5, cq = idx & 31;
    int ip = pt * 64 + r;
    if (ip < HWOUT) {
      bf16x4 t = *(const bf16x4*)(F + ((size_t)img * HWOUT + ip) * COUT + 128 + cq * 4);
      *(bf16x4*)(&Ls[r][cq * 4]) = t;
    }
  }
  __syncthreads();
#pragma unroll
  for (int i = 0; i < 8; ++i) {
    int idx = i * 256 + tid;
    int c = idx >> 4, iq = idx & 15;
    int ipb = pt * 64 + iq * 4;
    if (ipb + 3 < HWOUT) {
      bf16x4 v;
      v[0] = Ls[iq * 4 + 0][c];
      v[1] = Ls[iq * 4 + 1][c];
      v[2] = Ls[iq * 4 + 2][c];
      v[3] = Ls[iq * 4 + 3][c];
      *(bf16x4*)(VT + ((size_t)pair * 128 + c) * NJ + n * HWOUT + ipb) = v;
    }
  }
}

// ======================= K6: O = P * V, fused distance =======================
__global__ __launch_bounds__(256) void k_out(const char* __restrict__ Pbytes,
                                             const bf16* __restrict__ VT,
                                             const bf16* __restrict__ F,
                                             float* __restrict__ dist) {
  __shared__ __align__(16) bf16 As[96 * 128];   // rows 256B, 16 chunks
  __shared__ __align__(16) bf16 Bs[128 * 128];
  const int tid = threadIdx.x, lane = tid & 63, wave = tid >> 6;
  const int mt = blockIdx.x, pair = blockIdx.y;
  const int b = pair / 5;

  unsigned aByte[6]; int aGv[6];
#pragma unroll
  for (int i = 0; i < 6; ++i) {
    int issue = wave * 6 + i;
    int m = issue * 4 + (lane >> 4);
    int s_ = lane & 15;
    int g = s_ ^ (m & 7);
    int pm = mt * 96 + m;
    if (pm >= HWOUT) pm = 0;
    aByte[i] = (unsigned)((pair * HWOUT + pm) * 8000) + (unsigned)g * 16;
    aGv[i] = g;
  }
  unsigned bElem[8]; int bGv[8];
#pragma unroll
  for (int i = 0; i < 8; ++i) {
    int issue = wave * 8 + i;
    int c = issue * 4 + (lane >> 4);
    int s_ = lane & 15;
    int g = s_ ^ (c & 7);
    bElem[i] = (unsigned)((pair * 128 + c) * NJ) + (unsigned)g * 8;
    bGv[i] = g;
  }

  f32x16 acc[3];
#pragma unroll
  for (int mi = 0; mi < 3; ++mi)
#pragma unroll
    for (int r = 0; r < 16; ++r) acc[mi][r] = 0.f;

  const int mr = lane & 31;
  for (int step = 0; step < 16; ++step) {
    const int k0 = step * 128;
    const int nch = (step < 15) ? 16 : 10;
#pragma unroll
    for (int i = 0; i < 6; ++i) {
      if (aGv[i] < nch)
        gl2lds16(Pbytes + aByte[i] + k0 * 2, (char*)As + (wave * 6 + i) * 1024);
    }
#pragma unroll
    for (int i = 0; i < 8; ++i) {
      if (bGv[i] < nch)
        gl2lds16(VT + bElem[i] + k0, (char*)Bs + (wave * 8 + i) * 1024);
    }
    __syncthreads();
    auto body = [&](int kq) {
      const int chunk = kq * 2 + (lane >> 5);
      bf16x8 a[3], bb;
#pragma unroll
      for (int mi = 0; mi < 3; ++mi) {
        int m = mi * 32 + mr;
        int slot = chunk ^ (m & 7);
        a[mi] = *(const bf16x8*)((const char*)As + m * 256 + slot * 16);
      }
      {
        int n = wave * 32 + mr;
        int slot = chunk ^ (n & 7);
        bb = *(const bf16x8*)((const char*)Bs + n * 256 + slot * 16);
      }
#pragma unroll
      for (int mi = 0; mi < 3; ++mi)
        acc[mi] = __builtin_amdgcn_mfma_f32_32x32x16_bf16(a[mi], bb, acc[mi], 0, 0, 0);
    };
    if (step < 15) {
#pragma unroll
      for (int kq = 0; kq < 8; ++kq) body(kq);
    } else {
#pragma unroll
      for (int kq = 0; kq < 5; ++kq) body(kq);
    }
    __syncthreads();
  }

  const int col = lane & 31, hi = lane >> 5;
  float psum = 0.f;
#pragma unroll
  for (int mi = 0; mi < 3; ++mi)
#pragma unroll
    for (int r = 0; r < 16; ++r) {
      int row = (r & 3) + 8 * (r >> 2) + 4 * hi;
      int pix = mt * 96 + mi * 32 + row;
      if (pix < HWOUT) {
        int c = wave * 32 + col;
        float qv = (float)F[((size_t)b * HWOUT + pix) * COUT + 128 + c];
        float d = qv - acc[mi][r];
        psum += d * d;
      }
    }
  for (int off = 32; off > 0; off >>= 1) psum += __shfl_down(psum, off);
  __shared__ float ws4[4];
  if (lane == 0) ws4[wave] = psum;
  __syncthreads();
  if (tid == 0) atomicAdd(dist + pair, ws4[0] + ws4[1] + ws4[2] + ws4[3]);
}

// ======================= K7: finalize =======================
__global__ void k_final(const float* __restrict__ dist, float* __restrict__ out) {
  int i = threadIdx.x;
  if (i < NPAIR) out[i] = -dist[i] * (1.0f / HWOUT);
}

// ======================= launch =======================
extern "C" void kernel_launch(void* const* d_in, const int* in_sizes, int n_in,
                              void* d_out, int out_size, void* d_ws, size_t ws_size,
                              hipStream_t stream) {
  (void)in_sizes; (void)n_in; (void)out_size;
  if (ws_size < WS_NEED) return;  // workspace too small: visibly fail rather than corrupt

  const float* img_q = (const float*)d_in[0];
  const float* img_s = (const float*)d_in[1];
  const float* w_qk  = (const float*)d_in[2];
  const float* w_v   = (const float*)d_in[3];
  const float* w_ms  = (const float*)d_in[4];

  char* ws = (char*)d_ws;
  bf16*  Wb   = (bf16*)(ws + OFF_WB);
  bf16*  F    = (bf16*)(ws + OFF_F);
  bf16*  VT   = (bf16*)(ws + OFF_VT);
  float* dist = (float*)(ws + OFF_DIST);
  bf16*  R    = (bf16*)(ws + OFF_R);
  float* S    = (float*)(ws + OFF_R);  // aliases R (R dead after conv)

  hipMemsetAsync(dist, 0, NPAIR * sizeof(float), stream);
  k_wcomb  <<<dim3(72, 4),      256, 0, stream>>>(w_qk, w_v, w_ms, Wb);
  k_repack <<<dim3(27, 8, 208), 256, 0, stream>>>(img_q, img_s, R);
  k_conv   <<<dim3(650),        256, 0, stream>>>(R, Wb, F);
  k_sim    <<<dim3(5, 8, 40),   256, 0, stream>>>(F, S);
  k_softmax<<<dim3(16000),      256, 0, stream>>>(S);
  k_vt     <<<dim3(7, 5, 40),   256, 0, stream>>>(F, VT);
  k_out    <<<dim3(5, 40),      256, 0, stream>>>((const char*)S, VT, F, dist);
  k_final  <<<1, 64,             0, stream>>>(dist, (float*)d_out);
}

// Round 2
// 1401.617 us; speedup vs baseline: 1.0419x; 1.0006x over previous
//
#include <hip/hip_runtime.h>

// ---------------- problem constants ----------------
#define DIMC   512
#define HWIN   1681   // 41*41
#define WIN_   41
#define HWOUT  400    // 20*20
#define COUT   256    // 128 qk-proj + 128 v-proj
#define KD     4608   // 512*9
#define NIMG   208    // 8 query + 200 supports
#define NPAIR  40     // 8 * 5
#define NJ     2000   // 5 * 400
#define MTOT   83200  // 208 * 400 flattened conv-GEMM rows

typedef __bf16 bf16;
typedef __bf16 bf16x4 __attribute__((ext_vector_type(4)));
typedef __bf16 bf16x8 __attribute__((ext_vector_type(8)));
typedef float  f32x16 __attribute__((ext_vector_type(16)));

// ---------------- workspace layout (bytes) ----------------
// Wb  : bf16 [256][4608]       (combined conv weights, k = t*512+c, row-major n)
// F   : bf16 [208][400][256]   (conv output, channel-last)
// VT  : bf16 [40][128][2000]   (V transposed per (b,k))
// dist: f32  [40]
// R   : bf16 [208][1681][512]  (channel-last input) -- aliased by S f32 [40][400][2000]
#define OFF_WB   0ull
#define OFF_F    2359296ull
#define OFF_VT   44957696ull
#define OFF_DIST 65437696ull
#define OFF_R    65437952ull
#define WS_NEED  (OFF_R + 358039552ull)

__device__ __forceinline__ void gl2lds16(const void* g, void* l) {
  __builtin_amdgcn_global_load_lds((const __attribute__((address_space(1))) unsigned int*)g,
                                   (__attribute__((address_space(3))) unsigned int*)l,
                                   16, 0, 0);
}

// ======================= K1: combine weights =======================
// C[n][p] = sum_o W[n][o] * w_ms[o][p], p = c*9+t ; store Wb[n][t*512+c] (bf16)
__global__ __launch_bounds__(256) void k_wcomb(const float* __restrict__ wqk,
                                               const float* __restrict__ wv,
                                               const float* __restrict__ wms,
                                               bf16* __restrict__ Wb) {
  __shared__ float As[64][33];
  __shared__ float Bs[32][65];
  const int tid = threadIdx.x;
  const int bp = blockIdx.x, bn = blockIdx.y;
  const int tx = tid & 15, ty = tid >> 4;
  float acc[4][4] = {};
  for (int ko = 0; ko < 512; ko += 32) {
#pragma unroll
    for (int i = 0; i < 8; ++i) {
      int idx = tid + i * 256;
      int r = idx >> 5, c = idx & 31;
      int row = bn * 64 + r;
      As[r][c] = (row < 128) ? wqk[row * 512 + ko + c] : wv[(row - 128) * 512 + ko + c];
    }
#pragma unroll
    for (int i = 0; i < 8; ++i) {
      int idx = tid + i * 256;
      int r = idx >> 6, c = idx & 63;
      Bs[r][c] = wms[(size_t)(ko + r) * KD + bp * 64 + c];
    }
    __syncthreads();
#pragma unroll
    for (int kk = 0; kk < 32; ++kk) {
      float av[4], bv[4];
#pragma unroll
      for (int i = 0; i < 4; ++i) av[i] = As[ty * 4 + i][kk];
#pragma unroll
      for (int j = 0; j < 4; ++j) bv[j] = Bs[kk][tx * 4 + j];
#pragma unroll
      for (int i = 0; i < 4; ++i)
#pragma unroll
        for (int j = 0; j < 4; ++j) acc[i][j] += av[i] * bv[j];
    }
    __syncthreads();
  }
#pragma unroll
  for (int i = 0; i < 4; ++i)
#pragma unroll
    for (int j = 0; j < 4; ++j) {
      int n = bn * 64 + ty * 4 + i;
      int p = bp * 64 + tx * 4 + j;
      int c = p / 9, t = p - c * 9;
      Wb[(size_t)n * KD + t * DIMC + c] = (bf16)acc[i][j];
    }
}

// ======================= K2: repack input to channel-last bf16 =======================
__global__ __launch_bounds__(256) void k_repack(const float* __restrict__ q,
                                                const float* __restrict__ s,
                                                bf16* __restrict__ R) {
  __shared__ bf16 Ls[64][65];   // [channel][x]
  const int tid = threadIdx.x;
  const int bx = blockIdx.x, by = blockIdx.y, img = blockIdx.z;
  const float* src = (img < 8) ? (q + (size_t)img * DIMC * HWIN)
                               : (s + (size_t)(img - 8) * DIMC * HWIN);
  const int x0 = bx * 64, c0 = by * 64;
#pragma unroll
  for (int i = 0; i < 16; ++i) {
    int idx = i * 256 + tid;
    int r = idx >> 6, cx = idx & 63;
    int xx = x0 + cx;
    if (xx < HWIN) Ls[r][cx] = (bf16)src[(size_t)(c0 + r) * HWIN + xx];
  }
  __syncthreads();
#pragma unroll
  for (int i = 0; i < 4; ++i) {
    int idx = i * 256 + tid;
    int prow = idx >> 4, cq = idx & 15;
    int xx = x0 + prow;
    if (xx < HWIN) {
      bf16x4 v;
      v[0] = Ls[cq * 4 + 0][prow];
      v[1] = Ls[cq * 4 + 1][prow];
      v[2] = Ls[cq * 4 + 2][prow];
      v[3] = Ls[cq * 4 + 3][prow];
      *(bf16x4*)(R + ((size_t)img * HWIN + xx) * DIMC + c0 + cq * 4) = v;
    }
  }
}

// ======================= K3: conv as ONE flat implicit GEMM (bf16 MFMA) =======================
__global__ __launch_bounds__(256, 2) void k_conv(const bf16* __restrict__ R,
                                                 const bf16* __restrict__ Wb,
                                                 bf16* __restrict__ F) {
  __shared__ __align__(16) bf16 As[128 * 64];   // rows 128B, 8 chunks, XOR(m&7) swizzle
  __shared__ __align__(16) bf16 Bs[256 * 64];
  const int tid = threadIdx.x;
  const int lane = tid & 63, wave = tid >> 6;
  const int blk = blockIdx.x;

  unsigned aPix[4];
#pragma unroll
  for (int i = 0; i < 4; ++i) {
    int issue = wave * 4 + i;
    int m = issue * 8 + (lane >> 3);
    int g = (lane & 7) ^ (m & 7);
    int gm = blk * 128 + m;              // global output row 0..83199
    int img = gm / 400, p = gm - img * 400;
    int oy = p / 20, ox = p - oy * 20;
    aPix[i] = (unsigned)((img * HWIN + (2 * oy) * WIN_ + 2 * ox) * DIMC) + (unsigned)g * 8;
  }
  unsigned bOfs[8];
#pragma unroll
  for (int i = 0; i < 8; ++i) {
    int ib = wave * 8 + i;
    int n = ib * 8 + (lane >> 3);
    int g = (lane & 7) ^ (n & 7);
    bOfs[i] = (unsigned)n * KD + (unsigned)g * 8;
  }

  f32x16 acc[4][2];
#pragma unroll
  for (int mi = 0; mi < 4; ++mi)
#pragma unroll
    for (int ni = 0; ni < 2; ++ni)
#pragma unroll
      for (int r = 0; r < 16; ++r) acc[mi][ni][r] = 0.f;

  for (int t = 0; t < 9; ++t) {
    const int dy = t / 3, dx = t - dy * 3;
    const unsigned tapoff = (unsigned)((dy * WIN_ + dx) * DIMC);
    for (int cc = 0; cc < 8; ++cc) {
      const unsigned c0 = (unsigned)(cc * 64);
#pragma unroll
      for (int i = 0; i < 4; ++i) {
        int issue = wave * 4 + i;
        gl2lds16(R + aPix[i] + tapoff + c0, (char*)As + issue * 1024);
      }
#pragma unroll
      for (int i = 0; i < 8; ++i) {
        int ib = wave * 8 + i;
        gl2lds16(Wb + bOfs[i] + (unsigned)(t * DIMC) + c0, (char*)Bs + ib * 1024);
      }
      __syncthreads();
      const int mr = lane & 31;
#pragma unroll
      for (int kq = 0; kq < 4; ++kq) {
        const int chunk = kq * 2 + (lane >> 5);
        bf16x8 a[4], b[2];
#pragma unroll
        for (int mi = 0; mi < 4; ++mi) {
          int m = mi * 32 + mr;
          int slot = chunk ^ (m & 7);
          a[mi] = *(const bf16x8*)((const char*)As + m * 128 + slot * 16);
        }
#pragma unroll
        for (int ni = 0; ni < 2; ++ni) {
          int n = wave * 64 + ni * 32 + mr;
          int slot = chunk ^ (n & 7);
          b[ni] = *(const bf16x8*)((const char*)Bs + n * 128 + slot * 16);
        }
#pragma unroll
        for (int mi = 0; mi < 4; ++mi)
#pragma unroll
          for (int ni = 0; ni < 2; ++ni)
            acc[mi][ni] = __builtin_amdgcn_mfma_f32_32x32x16_bf16(a[mi], b[ni], acc[mi][ni], 0, 0, 0);
      }
      __syncthreads();
    }
  }
  const int col = lane & 31, hi = lane >> 5;
#pragma unroll
  for (int mi = 0; mi < 4; ++mi)
#pragma unroll
    for (int ni = 0; ni < 2; ++ni)
#pragma unroll
      for (int r = 0; r < 16; ++r) {
        int row = (r & 3) + 8 * (r >> 2) + 4 * hi;
        int gm = blk * 128 + mi * 32 + row;
        int ch = wave * 64 + ni * 32 + col;
        F[(size_t)gm * COUT + ch] = (bf16)acc[mi][ni][r];
      }
}

// ======================= K4: sim = Q K^T * scale =======================
__global__ __launch_bounds__(256) void k_sim(const bf16* __restrict__ F,
                                             float* __restrict__ S) {
  __shared__ __align__(16) bf16 As[96 * 64];
  __shared__ __align__(16) bf16 Bs[256 * 64];
  const int tid = threadIdx.x, lane = tid & 63, wave = tid >> 6;
  const int mt = blockIdx.x, nt = blockIdx.y, pair = blockIdx.z;
  const int b = pair / 5, kidx = pair - b * 5;
  const int simg = 8 + b * 25 + kidx * 5;

  unsigned aBase[3];
#pragma unroll
  for (int i = 0; i < 3; ++i) {
    int issue = wave * 3 + i;
    int m = issue * 8 + (lane >> 3);
    int g = (lane & 7) ^ (m & 7);
    int pm = mt * 96 + m;
    if (pm >= HWOUT) pm = 0;
    aBase[i] = (unsigned)((b * HWOUT + pm) * COUT) + (unsigned)g * 8;
  }
  unsigned bBase[8];
#pragma unroll
  for (int i = 0; i < 8; ++i) {
    int ib = wave * 8 + i;
    int r = ib * 8 + (lane >> 3);
    int g = (lane & 7) ^ (r & 7);
    int jj = nt * 256 + r;
    if (jj >= NJ) jj = 0;
    int nimg = jj / HWOUT, ip = jj - nimg * HWOUT;
    bBase[i] = (unsigned)(((simg + nimg) * HWOUT + ip) * COUT) + (unsigned)g * 8;
  }

  f32x16 acc[3][2];
#pragma unroll
  for (int mi = 0; mi < 3; ++mi)
#pragma unroll
    for (int ni = 0; ni < 2; ++ni)
#pragma unroll
      for (int r = 0; r < 16; ++r) acc[mi][ni][r] = 0.f;

  for (int ks = 0; ks < 2; ++ks) {
    const int c0 = ks * 64;
#pragma unroll
    for (int i = 0; i < 3; ++i)
      gl2lds16(F + aBase[i] + c0, (char*)As + (wave * 3 + i) * 1024);
#pragma unroll
    for (int i = 0; i < 8; ++i)
      gl2lds16(F + bBase[i] + c0, (char*)Bs + (wave * 8 + i) * 1024);
    __syncthreads();
    const int mr = lane & 31;
#pragma unroll
    for (int kq = 0; kq < 4; ++kq) {
      const int chunk = kq * 2 + (lane >> 5);
      bf16x8 a[3], b[2];
#pragma unroll
      for (int mi = 0; mi < 3; ++mi) {
        int m = mi * 32 + mr;
        int slot = chunk ^ (m & 7);
        a[mi] = *(const bf16x8*)((const char*)As + m * 128 + slot * 16);
      }
#pragma unroll
      for (int ni = 0; ni < 2; ++ni) {
        int n = wave * 64 + ni * 32 + mr;
        int slot = chunk ^ (n & 7);
        b[ni] = *(const bf16x8*)((const char*)Bs + n * 128 + slot * 16);
      }
#pragma unroll
      for (int mi = 0; mi < 3; ++mi)
#pragma unroll
        for (int ni = 0; ni < 2; ++ni)
          acc[mi][ni] = __builtin_amdgcn_mfma_f32_32x32x16_bf16(a[mi], b[ni], acc[mi][ni], 0, 0, 0);
    }
    __syncthreads();
  }
  const float scale = 0.08838834764831845f;  // 128^-0.5
  const int col = lane & 31, hi = lane >> 5;
#pragma unroll
  for (int mi = 0; mi < 3; ++mi)
#pragma unroll
    for (int ni = 0; ni < 2; ++ni)
#pragma unroll
      for (int r = 0; r < 16; ++r) {
        int row = (r & 3) + 8 * (r >> 2) + 4 * hi;
        int pix = mt * 96 + mi * 32 + row;
        int j = nt * 256 + wave * 64 + ni * 32 + col;
        if (pix < HWOUT && j < NJ)
          S[((size_t)pair * HWOUT + pix) * NJ + j] = acc[mi][ni][r] * scale;
      }
}

// ======================= K5b: build VT[pair][c][j] =======================
__global__ __launch_bounds__(256) void k_vt(const bf16* __restrict__ F,
                                            bf16* __restrict__ VT) {
  __shared__ bf16 Ls[64][132];  // [ip-local][c]
  const int tid = threadIdx.x;
  const int pt = blockIdx.x, n = blockIdx.y, pair = blockIdx.z;
  const int b = pair / 5, kidx = pair - b * 5;
  const int img = 8 + b * 25 + kidx * 5 + n;
#pragma unroll
  for (int i = 0; i < 8; ++i) {
    int idx = i * 256 + tid;
    int r = idx >> 5, cq = idx & 31;
    int ip = pt * 64 + r;
    if (ip < HWOUT) {
      bf16x4 t = *(const bf16x4*)(F + ((size_t)img * HWOUT + ip) * COUT + 128 + cq * 4);
      *(bf16x4*)(&Ls[r][cq * 4]) = t;
    }
  }
  __syncthreads();
#pragma unroll
  for (int i = 0; i < 8; ++i) {
    int idx = i * 256 + tid;
    int c = idx >> 4, iq = idx & 15;
    int ipb = pt * 64 + iq * 4;
    if (ipb + 3 < HWOUT) {
      bf16x4 v;
      v[0] = Ls[iq * 4 + 0][c];
      v[1] = Ls[iq * 4 + 1][c];
      v[2] = Ls[iq * 4 + 2][c];
      v[3] = Ls[iq * 4 + 3][c];
      *(bf16x4*)(VT + ((size_t)pair * 128 + c) * NJ + n * HWOUT + ipb) = v;
    }
  }
}

// ======================= K6: online-softmax + O = P*V + fused distance =======================
// Reads S (fp32) directly; flash-style running max/sum with O-rescale. Replaces k_softmax+k_out.
__global__ __launch_bounds__(256, 2) void k_out(const float* __restrict__ S,
                                                const bf16* __restrict__ VT,
                                                const bf16* __restrict__ F,
                                                float* __restrict__ dist) {
  __shared__ __align__(16) bf16 As[96 * 128];   // P-tile: 96 rows x 256B (16 chunks, XOR(r&7))
  __shared__ __align__(16) bf16 Bs[128 * 128];  // VT-tile: 128 c-rows x 256B
  __shared__ float mtab[96], ltab[96], fac[96];
  const int tid = threadIdx.x, lane = tid & 63, wave = tid >> 6;
  const int mt = blockIdx.x, pair = blockIdx.y;
  const int b = pair / 5;

  // B staging addresses (unchanged from proven kernel)
  unsigned bElem[8]; int bGv[8];
#pragma unroll
  for (int i = 0; i < 8; ++i) {
    int issue = wave * 8 + i;
    int c = issue * 4 + (lane >> 4);
    int s_ = lane & 15;
    int g = s_ ^ (c & 7);
    bElem[i] = (unsigned)((pair * 128 + c) * NJ) + (unsigned)g * 8;
    bGv[i] = g;
  }

  // stage-thread mapping: waves 0..2 stage S (2 threads per row), wave 3 idle in stage phase
  const int sr = tid >> 1;          // row 0..127; valid < 96
  const int sh = tid & 1;           // half: j-local [sh*64, sh*64+64)
  const bool srow_on = (sr < 96);
  int pixr = mt * 96 + sr;
  if (pixr >= HWOUT) pixr = 0;      // clamped rows: load real data, results discarded
  const float* srow = S + (size_t)(pair * HWOUT + pixr) * NJ + sh * 64;

  if (tid < 96) { mtab[tid] = -1e30f; ltab[tid] = 0.f; }

  f32x16 acc[3];
#pragma unroll
  for (int mi = 0; mi < 3; ++mi)
#pragma unroll
    for (int r = 0; r < 16; ++r) acc[mi][r] = 0.f;

  __syncthreads();
  const int mr = lane & 31;

  for (int step = 0; step < 16; ++step) {
    const int k0 = step * 128;
    const int nch = (step < 15) ? 16 : 10;
    // 1) issue B (VT) global->LDS
#pragma unroll
    for (int i = 0; i < 8; ++i) {
      if (bGv[i] < nch)
        gl2lds16(VT + bElem[i] + k0, (char*)Bs + (wave * 8 + i) * 1024);
    }
    // 2) stage S-tile -> regs, online softmax -> P bf16 -> As
    float p[64];
    float m_new = -1e30f, fac_r = 1.0f;
    if (srow_on) {
      float rowmax = -1e30f;
      const float* sp = srow + k0;
#pragma unroll
      for (int i = 0; i < 16; ++i) {
        int jl = sh * 64 + i * 4;
        float4 f;
        if (k0 + jl < NJ) f = *(const float4*)(sp + i * 4);
        else { f.x = -1e30f; f.y = -1e30f; f.z = -1e30f; f.w = -1e30f; }
        p[i * 4 + 0] = f.x; p[i * 4 + 1] = f.y; p[i * 4 + 2] = f.z; p[i * 4 + 3] = f.w;
        rowmax = fmaxf(rowmax, fmaxf(fmaxf(f.x, f.y), fmaxf(f.z, f.w)));
      }
      rowmax = fmaxf(rowmax, __shfl_xor(rowmax, 1));
      float m_old = mtab[sr];
      m_new = fmaxf(m_old, rowmax);
      fac_r = __expf(m_old - m_new);
      float psum = 0.f;
#pragma unroll
      for (int i = 0; i < 64; ++i) {
        p[i] = __expf(p[i] - m_new);
        psum += p[i];
      }
      psum += __shfl_xor(psum, 1);
      if (sh == 0) {
        mtab[sr] = m_new;
        fac[sr] = fac_r;
        ltab[sr] = ltab[sr] * fac_r + psum;
      }
#pragma unroll
      for (int ci = 0; ci < 8; ++ci) {
        bf16x8 w;
#pragma unroll
        for (int e = 0; e < 8; ++e) w[e] = (bf16)p[ci * 8 + e];
        int chunk = sh * 8 + ci;
        int slot = chunk ^ (sr & 7);
        *(bf16x8*)((char*)As + sr * 256 + slot * 16) = w;
      }
    }
    __syncthreads();
    // 3) rescale accumulator by this step's factors (LDS broadcast reads, no shuffles)
#pragma unroll
    for (int mi = 0; mi < 3; ++mi)
#pragma unroll
      for (int r = 0; r < 16; ++r) {
        int row = (r & 3) + 8 * (r >> 2) + 4 * (lane >> 5);
        acc[mi][r] *= fac[mi * 32 + row];
      }
    // 4) MFMA over this P-tile
    auto body = [&](int kq) {
      const int chunk = kq * 2 + (lane >> 5);
      bf16x8 a[3], bb;
#pragma unroll
      for (int mi = 0; mi < 3; ++mi) {
        int m = mi * 32 + mr;
        int slot = chunk ^ (m & 7);
        a[mi] = *(const bf16x8*)((const char*)As + m * 256 + slot * 16);
      }
      {
        int n = wave * 32 + mr;
        int slot = chunk ^ (n & 7);
        bb = *(const bf16x8*)((const char*)Bs + n * 256 + slot * 16);
      }
#pragma unroll
      for (int mi = 0; mi < 3; ++mi)
        acc[mi] = __builtin_amdgcn_mfma_f32_32x32x16_bf16(a[mi], bb, acc[mi], 0, 0, 0);
    };
    if (step < 15) {
#pragma unroll
      for (int kq = 0; kq < 8; ++kq) body(kq);
    } else {
#pragma unroll
      for (int kq = 0; kq < 5; ++kq) body(kq);
    }
    __syncthreads();
  }

  // epilogue: O = acc / l, distance vs query-V
  const int col = lane & 31, hi = lane >> 5;
  float psum = 0.f;
#pragma unroll
  for (int mi = 0; mi < 3; ++mi)
#pragma unroll
    for (int r = 0; r < 16; ++r) {
      int row = (r & 3) + 8 * (r >> 2) + 4 * hi;
      int pix = mt * 96 + mi * 32 + row;
      if (pix < HWOUT) {
        float l = ltab[mi * 32 + row];
        float o = acc[mi][r] / l;
        int c = wave * 32 + col;
        float qv = (float)F[((size_t)b * HWOUT + pix) * COUT + 128 + c];
        float d = qv - o;
        psum += d * d;
      }
    }
  for (int off = 32; off > 0; off >>= 1) psum += __shfl_down(psum, off);
  __shared__ float ws4[4];
  if (lane == 0) ws4[wave] = psum;
  __syncthreads();
  if (tid == 0) atomicAdd(dist + pair, ws4[0] + ws4[1] + ws4[2] + ws4[3]);
}

// ======================= K7: finalize =======================
__global__ void k_final(const float* __restrict__ dist, float* __restrict__ out) {
  int i = threadIdx.x;
  if (i < NPAIR) out[i] = -dist[i] * (1.0f / HWOUT);
}

// ======================= launch =======================
extern "C" void kernel_launch(void* const* d_in, const int* in_sizes, int n_in,
                              void* d_out, int out_size, void* d_ws, size_t ws_size,
                              hipStream_t stream) {
  (void)in_sizes; (void)n_in; (void)out_size;
  if (ws_size < WS_NEED) return;  // workspace too small: visibly fail rather than corrupt

  const float* img_q = (const float*)d_in[0];
  const float* img_s = (const float*)d_in[1];
  const float* w_qk  = (const float*)d_in[2];
  const float* w_v   = (const float*)d_in[3];
  const float* w_ms  = (const float*)d_in[4];

  char* ws = (char*)d_ws;
  bf16*  Wb   = (bf16*)(ws + OFF_WB);
  bf16*  F    = (bf16*)(ws + OFF_F);
  bf16*  VT   = (bf16*)(ws + OFF_VT);
  float* dist = (float*)(ws + OFF_DIST);
  bf16*  R    = (bf16*)(ws + OFF_R);
  float* S    = (float*)(ws + OFF_R);  // aliases R (R dead after conv)

  hipMemsetAsync(dist, 0, NPAIR * sizeof(float), stream);
  k_wcomb  <<<dim3(72, 4),      256, 0, stream>>>(w_qk, w_v, w_ms, Wb);
  k_repack <<<dim3(27, 8, 208), 256, 0, stream>>>(img_q, img_s, R);
  k_conv   <<<dim3(650),        256, 0, stream>>>(R, Wb, F);
  k_sim    <<<dim3(5, 8, 40),   256, 0, stream>>>(F, S);
  k_vt     <<<dim3(7, 5, 40),   256, 0, stream>>>(F, VT);
  k_out    <<<dim3(5, 40),      256, 0, stream>>>(S, VT, F, dist);
  k_final  <<<1, 64,             0, stream>>>(dist, (float*)d_out);
}

// Round 3
// 1395.094 us; speedup vs baseline: 1.0468x; 1.0047x over previous
//
#include <hip/hip_runtime.h>

// ---------------- problem constants ----------------
#define DIMC   512
#define HWIN   1681   // 41*41
#define WIN_   41
#define HWOUT  400    // 20*20
#define COUT   256    // 128 qk-proj + 128 v-proj
#define KD     4608   // 512*9
#define NIMG   208    // 8 query + 200 supports
#define NPAIR  40     // 8 * 5
#define NJ     2000   // 5 * 400
#define MTOT   83200  // 208 * 400 flattened conv-GEMM rows

typedef __bf16 bf16;
typedef __bf16 bf16x4 __attribute__((ext_vector_type(4)));
typedef __bf16 bf16x8 __attribute__((ext_vector_type(8)));
typedef float  f32x16 __attribute__((ext_vector_type(16)));

// ---------------- workspace layout (bytes) ----------------
// Wb  : bf16 [256][4608]       (combined conv weights, k = t*512+c, row-major n)
// F   : bf16 [208][400][256]   (conv output, channel-last)
// VT  : bf16 [40][128][2000]   (V transposed per (b,k))
// dist: f32  [40]
// R   : bf16 [208][1681][512]  (channel-last input) -- aliased by S f32 [40][400][2000]
#define OFF_WB   0ull
#define OFF_F    2359296ull
#define OFF_VT   44957696ull
#define OFF_DIST 65437696ull
#define OFF_R    65437952ull
#define WS_NEED  (OFF_R + 358039552ull)

__device__ __forceinline__ void gl2lds16(const void* g, void* l) {
  __builtin_amdgcn_global_load_lds((const __attribute__((address_space(1))) unsigned int*)g,
                                   (__attribute__((address_space(3))) unsigned int*)l,
                                   16, 0, 0);
}

// ======================= K1: combine weights =======================
// C[n][p] = sum_o W[n][o] * w_ms[o][p], p = c*9+t ; store Wb[n][t*512+c] (bf16)
__global__ __launch_bounds__(256) void k_wcomb(const float* __restrict__ wqk,
                                               const float* __restrict__ wv,
                                               const float* __restrict__ wms,
                                               bf16* __restrict__ Wb) {
  __shared__ float As[64][33];
  __shared__ float Bs[32][65];
  const int tid = threadIdx.x;
  const int bp = blockIdx.x, bn = blockIdx.y;
  const int tx = tid & 15, ty = tid >> 4;
  float acc[4][4] = {};
  for (int ko = 0; ko < 512; ko += 32) {
#pragma unroll
    for (int i = 0; i < 8; ++i) {
      int idx = tid + i * 256;
      int r = idx >> 5, c = idx & 31;
      int row = bn * 64 + r;
      As[r][c] = (row < 128) ? wqk[row * 512 + ko + c] : wv[(row - 128) * 512 + ko + c];
    }
#pragma unroll
    for (int i = 0; i < 8; ++i) {
      int idx = tid + i * 256;
      int r = idx >> 6, c = idx & 63;
      Bs[r][c] = wms[(size_t)(ko + r) * KD + bp * 64 + c];
    }
    __syncthreads();
#pragma unroll
    for (int kk = 0; kk < 32; ++kk) {
      float av[4], bv[4];
#pragma unroll
      for (int i = 0; i < 4; ++i) av[i] = As[ty * 4 + i][kk];
#pragma unroll
      for (int j = 0; j < 4; ++j) bv[j] = Bs[kk][tx * 4 + j];
#pragma unroll
      for (int i = 0; i < 4; ++i)
#pragma unroll
        for (int j = 0; j < 4; ++j) acc[i][j] += av[i] * bv[j];
    }
    __syncthreads();
  }
#pragma unroll
  for (int i = 0; i < 4; ++i)
#pragma unroll
    for (int j = 0; j < 4; ++j) {
      int n = bn * 64 + ty * 4 + i;
      int p = bp * 64 + tx * 4 + j;
      int c = p / 9, t = p - c * 9;
      Wb[(size_t)n * KD + t * DIMC + c] = (bf16)acc[i][j];
    }
}

// ======================= K2: repack input to channel-last bf16 =======================
__global__ __launch_bounds__(256) void k_repack(const float* __restrict__ q,
                                                const float* __restrict__ s,
                                                bf16* __restrict__ R) {
  __shared__ bf16 Ls[64][65];   // [channel][x]
  const int tid = threadIdx.x;
  const int bx = blockIdx.x, by = blockIdx.y, img = blockIdx.z;
  const float* src = (img < 8) ? (q + (size_t)img * DIMC * HWIN)
                               : (s + (size_t)(img - 8) * DIMC * HWIN);
  const int x0 = bx * 64, c0 = by * 64;
#pragma unroll
  for (int i = 0; i < 16; ++i) {
    int idx = i * 256 + tid;
    int r = idx >> 6, cx = idx & 63;
    int xx = x0 + cx;
    if (xx < HWIN) Ls[r][cx] = (bf16)src[(size_t)(c0 + r) * HWIN + xx];
  }
  __syncthreads();
#pragma unroll
  for (int i = 0; i < 4; ++i) {
    int idx = i * 256 + tid;
    int prow = idx >> 4, cq = idx & 15;
    int xx = x0 + prow;
    if (xx < HWIN) {
      bf16x4 v;
      v[0] = Ls[cq * 4 + 0][prow];
      v[1] = Ls[cq * 4 + 1][prow];
      v[2] = Ls[cq * 4 + 2][prow];
      v[3] = Ls[cq * 4 + 3][prow];
      *(bf16x4*)(R + ((size_t)img * HWIN + xx) * DIMC + c0 + cq * 4) = v;
    }
  }
}

// ======================= K3: conv as ONE flat implicit GEMM (bf16 MFMA) =======================
__global__ __launch_bounds__(256, 2) void k_conv(const bf16* __restrict__ R,
                                                 const bf16* __restrict__ Wb,
                                                 bf16* __restrict__ F) {
  __shared__ __align__(16) bf16 As[128 * 64];   // rows 128B, 8 chunks, XOR(m&7) swizzle
  __shared__ __align__(16) bf16 Bs[256 * 64];
  const int tid = threadIdx.x;
  const int lane = tid & 63, wave = tid >> 6;
  const int blk = blockIdx.x;

  unsigned aPix[4];
#pragma unroll
  for (int i = 0; i < 4; ++i) {
    int issue = wave * 4 + i;
    int m = issue * 8 + (lane >> 3);
    int g = (lane & 7) ^ (m & 7);
    int gm = blk * 128 + m;              // global output row 0..83199
    int img = gm / 400, p = gm - img * 400;
    int oy = p / 20, ox = p - oy * 20;
    aPix[i] = (unsigned)((img * HWIN + (2 * oy) * WIN_ + 2 * ox) * DIMC) + (unsigned)g * 8;
  }
  unsigned bOfs[8];
#pragma unroll
  for (int i = 0; i < 8; ++i) {
    int ib = wave * 8 + i;
    int n = ib * 8 + (lane >> 3);
    int g = (lane & 7) ^ (n & 7);
    bOfs[i] = (unsigned)n * KD + (unsigned)g * 8;
  }

  f32x16 acc[4][2];
#pragma unroll
  for (int mi = 0; mi < 4; ++mi)
#pragma unroll
    for (int ni = 0; ni < 2; ++ni)
#pragma unroll
      for (int r = 0; r < 16; ++r) acc[mi][ni][r] = 0.f;

  for (int t = 0; t < 9; ++t) {
    const int dy = t / 3, dx = t - dy * 3;
    const unsigned tapoff = (unsigned)((dy * WIN_ + dx) * DIMC);
    for (int cc = 0; cc < 8; ++cc) {
      const unsigned c0 = (unsigned)(cc * 64);
#pragma unroll
      for (int i = 0; i < 4; ++i) {
        int issue = wave * 4 + i;
        gl2lds16(R + aPix[i] + tapoff + c0, (char*)As + issue * 1024);
      }
#pragma unroll
      for (int i = 0; i < 8; ++i) {
        int ib = wave * 8 + i;
        gl2lds16(Wb + bOfs[i] + (unsigned)(t * DIMC) + c0, (char*)Bs + ib * 1024);
      }
      __syncthreads();
      const int mr = lane & 31;
#pragma unroll
      for (int kq = 0; kq < 4; ++kq) {
        const int chunk = kq * 2 + (lane >> 5);
        bf16x8 a[4], b[2];
#pragma unroll
        for (int mi = 0; mi < 4; ++mi) {
          int m = mi * 32 + mr;
          int slot = chunk ^ (m & 7);
          a[mi] = *(const bf16x8*)((const char*)As + m * 128 + slot * 16);
        }
#pragma unroll
        for (int ni = 0; ni < 2; ++ni) {
          int n = wave * 64 + ni * 32 + mr;
          int slot = chunk ^ (n & 7);
          b[ni] = *(const bf16x8*)((const char*)Bs + n * 128 + slot * 16);
        }
#pragma unroll
        for (int mi = 0; mi < 4; ++mi)
#pragma unroll
          for (int ni = 0; ni < 2; ++ni)
            acc[mi][ni] = __builtin_amdgcn_mfma_f32_32x32x16_bf16(a[mi], b[ni], acc[mi][ni], 0, 0, 0);
      }
      __syncthreads();
    }
  }
  const int col = lane & 31, hi = lane >> 5;
#pragma unroll
  for (int mi = 0; mi < 4; ++mi)
#pragma unroll
    for (int ni = 0; ni < 2; ++ni)
#pragma unroll
      for (int r = 0; r < 16; ++r) {
        int row = (r & 3) + 8 * (r >> 2) + 4 * hi;
        int gm = blk * 128 + mi * 32 + row;
        int ch = wave * 64 + ni * 32 + col;
        F[(size_t)gm * COUT + ch] = (bf16)acc[mi][ni][r];
      }
}

// ======================= K4: sim = Q K^T * scale =======================
__global__ __launch_bounds__(256) void k_sim(const bf16* __restrict__ F,
                                             float* __restrict__ S) {
  __shared__ __align__(16) bf16 As[96 * 64];
  __shared__ __align__(16) bf16 Bs[256 * 64];
  const int tid = threadIdx.x, lane = tid & 63, wave = tid >> 6;
  const int mt = blockIdx.x, nt = blockIdx.y, pair = blockIdx.z;
  const int b = pair / 5, kidx = pair - b * 5;
  const int simg = 8 + b * 25 + kidx * 5;

  unsigned aBase[3];
#pragma unroll
  for (int i = 0; i < 3; ++i) {
    int issue = wave * 3 + i;
    int m = issue * 8 + (lane >> 3);
    int g = (lane & 7) ^ (m & 7);
    int pm = mt * 96 + m;
    if (pm >= HWOUT) pm = 0;
    aBase[i] = (unsigned)((b * HWOUT + pm) * COUT) + (unsigned)g * 8;
  }
  unsigned bBase[8];
#pragma unroll
  for (int i = 0; i < 8; ++i) {
    int ib = wave * 8 + i;
    int r = ib * 8 + (lane >> 3);
    int g = (lane & 7) ^ (r & 7);
    int jj = nt * 256 + r;
    if (jj >= NJ) jj = 0;
    int nimg = jj / HWOUT, ip = jj - nimg * HWOUT;
    bBase[i] = (unsigned)(((simg + nimg) * HWOUT + ip) * COUT) + (unsigned)g * 8;
  }

  f32x16 acc[3][2];
#pragma unroll
  for (int mi = 0; mi < 3; ++mi)
#pragma unroll
    for (int ni = 0; ni < 2; ++ni)
#pragma unroll
      for (int r = 0; r < 16; ++r) acc[mi][ni][r] = 0.f;

  for (int ks = 0; ks < 2; ++ks) {
    const int c0 = ks * 64;
#pragma unroll
    for (int i = 0; i < 3; ++i)
      gl2lds16(F + aBase[i] + c0, (char*)As + (wave * 3 + i) * 1024);
#pragma unroll
    for (int i = 0; i < 8; ++i)
      gl2lds16(F + bBase[i] + c0, (char*)Bs + (wave * 8 + i) * 1024);
    __syncthreads();
    const int mr = lane & 31;
#pragma unroll
    for (int kq = 0; kq < 4; ++kq) {
      const int chunk = kq * 2 + (lane >> 5);
      bf16x8 a[3], b[2];
#pragma unroll
      for (int mi = 0; mi < 3; ++mi) {
        int m = mi * 32 + mr;
        int slot = chunk ^ (m & 7);
        a[mi] = *(const bf16x8*)((const char*)As + m * 128 + slot * 16);
      }
#pragma unroll
      for (int ni = 0; ni < 2; ++ni) {
        int n = wave * 64 + ni * 32 + mr;
        int slot = chunk ^ (n & 7);
        b[ni] = *(const bf16x8*)((const char*)Bs + n * 128 + slot * 16);
      }
#pragma unroll
      for (int mi = 0; mi < 3; ++mi)
#pragma unroll
        for (int ni = 0; ni < 2; ++ni)
          acc[mi][ni] = __builtin_amdgcn_mfma_f32_32x32x16_bf16(a[mi], b[ni], acc[mi][ni], 0, 0, 0);
    }
    __syncthreads();
  }
  const float scale = 0.08838834764831845f;  // 128^-0.5
  const int col = lane & 31, hi = lane >> 5;
#pragma unroll
  for (int mi = 0; mi < 3; ++mi)
#pragma unroll
    for (int ni = 0; ni < 2; ++ni)
#pragma unroll
      for (int r = 0; r < 16; ++r) {
        int row = (r & 3) + 8 * (r >> 2) + 4 * hi;
        int pix = mt * 96 + mi * 32 + row;
        int j = nt * 256 + wave * 64 + ni * 32 + col;
        if (pix < HWOUT && j < NJ)
          S[((size_t)pair * HWOUT + pix) * NJ + j] = acc[mi][ni][r] * scale;
      }
}

// ======================= K5b: build VT[pair][c][j] =======================
__global__ __launch_bounds__(256) void k_vt(const bf16* __restrict__ F,
                                            bf16* __restrict__ VT) {
  __shared__ bf16 Ls[64][132];  // [ip-local][c]
  const int tid = threadIdx.x;
  const int pt = blockIdx.x, n = blockIdx.y, pair = blockIdx.z;
  const int b = pair / 5, kidx = pair - b * 5;
  const int img = 8 + b * 25 + kidx * 5 + n;
#pragma unroll
  for (int i = 0; i < 8; ++i) {
    int idx = i * 256 + tid;
    int r = idx >> 5, cq = idx & 31;
    int ip = pt * 64 + r;
    if (ip < HWOUT) {
      bf16x4 t = *(const bf16x4*)(F + ((size_t)img * HWOUT + ip) * COUT + 128 + cq * 4);
      *(bf16x4*)(&Ls[r][cq * 4]) = t;
    }
  }
  __syncthreads();
#pragma unroll
  for (int i = 0; i < 8; ++i) {
    int idx = i * 256 + tid;
    int c = idx >> 4, iq = idx & 15;
    int ipb = pt * 64 + iq * 4;
    if (ipb + 3 < HWOUT) {
      bf16x4 v;
      v[0] = Ls[iq * 4 + 0][c];
      v[1] = Ls[iq * 4 + 1][c];
      v[2] = Ls[iq * 4 + 2][c];
      v[3] = Ls[iq * 4 + 3][c];
      *(bf16x4*)(VT + ((size_t)pair * 128 + c) * NJ + n * HWOUT + ipb) = v;
    }
  }
}

// ======================= K6: online-softmax + O = P*V + fused distance =======================
// BM=32 re-tile: grid (13, 40) = 520 blocks -> ~3 blocks/CU so cross-block TLP hides
// the stage phase (HBM S-loads + exp) under other blocks' MFMA. Same 2-barrier structure.
__global__ __launch_bounds__(256, 3) void k_out(const float* __restrict__ S,
                                                const bf16* __restrict__ VT,
                                                const bf16* __restrict__ F,
                                                float* __restrict__ dist) {
  __shared__ __align__(16) bf16 As[32 * 128];   // P-tile: 32 rows x 256B (16 chunks, XOR(r&7))
  __shared__ __align__(16) bf16 Bs[128 * 128];  // VT-tile: 128 c-rows x 256B
  __shared__ float mtab[32], ltab[32], fac[32];
  const int tid = threadIdx.x, lane = tid & 63, wave = tid >> 6;
  const int mt = blockIdx.x, pair = blockIdx.y;
  const int b = pair / 5;

  // B staging addresses (unchanged from proven kernel)
  unsigned bElem[8]; int bGv[8];
#pragma unroll
  for (int i = 0; i < 8; ++i) {
    int issue = wave * 8 + i;
    int c = issue * 4 + (lane >> 4);
    int s_ = lane & 15;
    int g = s_ ^ (c & 7);
    bElem[i] = (unsigned)((pair * 128 + c) * NJ) + (unsigned)g * 8;
    bGv[i] = g;
  }

  // stage-thread mapping: 8 threads per row, 16 j each
  const int sr = tid >> 3;          // row 0..31
  const int sh = tid & 7;           // j-chunk: [sh*16, sh*16+16)
  int pixr = mt * 32 + sr;
  if (pixr >= HWOUT) pixr = 0;      // clamped rows: load real data, results discarded
  const float* srow = S + (size_t)(pair * HWOUT + pixr) * NJ + sh * 16;

  if (tid < 32) { mtab[tid] = -1e30f; ltab[tid] = 0.f; }

  f32x16 acc;
#pragma unroll
  for (int r = 0; r < 16; ++r) acc[r] = 0.f;

  __syncthreads();
  const int mr = lane & 31;
  const int hi = lane >> 5;

  for (int step = 0; step < 16; ++step) {
    const int k0 = step * 128;
    const int nch = (step < 15) ? 16 : 10;
    // 1) issue B (VT) global->LDS
#pragma unroll
    for (int i = 0; i < 8; ++i) {
      if (bGv[i] < nch)
        gl2lds16(VT + bElem[i] + k0, (char*)Bs + (wave * 8 + i) * 1024);
    }
    // 2) stage S-tile -> regs, online softmax -> P bf16 -> As
    float p[16];
    {
      float rowmax = -1e30f;
      const float* sp = srow + k0;
#pragma unroll
      for (int i = 0; i < 4; ++i) {
        int jl = sh * 16 + i * 4;
        float4 f;
        if (k0 + jl < NJ) f = *(const float4*)(sp + i * 4);
        else { f.x = -1e30f; f.y = -1e30f; f.z = -1e30f; f.w = -1e30f; }
        p[i * 4 + 0] = f.x; p[i * 4 + 1] = f.y; p[i * 4 + 2] = f.z; p[i * 4 + 3] = f.w;
        rowmax = fmaxf(rowmax, fmaxf(fmaxf(f.x, f.y), fmaxf(f.z, f.w)));
      }
      rowmax = fmaxf(rowmax, __shfl_xor(rowmax, 1));
      rowmax = fmaxf(rowmax, __shfl_xor(rowmax, 2));
      rowmax = fmaxf(rowmax, __shfl_xor(rowmax, 4));
      float m_old = mtab[sr];
      float m_new = fmaxf(m_old, rowmax);
      float fac_r = __expf(m_old - m_new);
      float psum = 0.f;
#pragma unroll
      for (int i = 0; i < 16; ++i) {
        p[i] = __expf(p[i] - m_new);
        psum += p[i];
      }
      psum += __shfl_xor(psum, 1);
      psum += __shfl_xor(psum, 2);
      psum += __shfl_xor(psum, 4);
      if (sh == 0) {
        mtab[sr] = m_new;
        fac[sr] = fac_r;
        ltab[sr] = ltab[sr] * fac_r + psum;
      }
#pragma unroll
      for (int ci = 0; ci < 2; ++ci) {
        bf16x8 w;
#pragma unroll
        for (int e = 0; e < 8; ++e) w[e] = (bf16)p[ci * 8 + e];
        int chunk = sh * 2 + ci;
        int slot = chunk ^ (sr & 7);
        *(bf16x8*)((char*)As + sr * 256 + slot * 16) = w;
      }
    }
    __syncthreads();
    // 3) rescale accumulator by this step's factors (LDS broadcast reads)
#pragma unroll
    for (int r = 0; r < 16; ++r) {
      int row = (r & 3) + 8 * (r >> 2) + 4 * hi;
      acc[r] *= fac[row];
    }
    // 4) MFMA over this P-tile
    auto body = [&](int kq) {
      const int chunk = kq * 2 + hi;
      bf16x8 a, bb;
      {
        int slot = chunk ^ (mr & 7);
        a = *(const bf16x8*)((const char*)As + mr * 256 + slot * 16);
      }
      {
        int n = wave * 32 + mr;
        int slot = chunk ^ (n & 7);
        bb = *(const bf16x8*)((const char*)Bs + n * 256 + slot * 16);
      }
      acc = __builtin_amdgcn_mfma_f32_32x32x16_bf16(a, bb, acc, 0, 0, 0);
    };
    if (step < 15) {
#pragma unroll
      for (int kq = 0; kq < 8; ++kq) body(kq);
    } else {
#pragma unroll
      for (int kq = 0; kq < 5; ++kq) body(kq);
    }
    __syncthreads();
  }

  // epilogue: O = acc / l, distance vs query-V
  const int col = lane & 31;
  float psum = 0.f;
#pragma unroll
  for (int r = 0; r < 16; ++r) {
    int row = (r & 3) + 8 * (r >> 2) + 4 * hi;
    int pix = mt * 32 + row;
    if (pix < HWOUT) {
      float l = ltab[row];
      float o = acc[r] / l;
      int c = wave * 32 + col;
      float qv = (float)F[((size_t)b * HWOUT + pix) * COUT + 128 + c];
      float d = qv - o;
      psum += d * d;
    }
  }
  for (int off = 32; off > 0; off >>= 1) psum += __shfl_down(psum, off);
  __shared__ float ws4[4];
  if (lane == 0) ws4[wave] = psum;
  __syncthreads();
  if (tid == 0) atomicAdd(dist + pair, ws4[0] + ws4[1] + ws4[2] + ws4[3]);
}

// ======================= K7: finalize =======================
__global__ void k_final(const float* __restrict__ dist, float* __restrict__ out) {
  int i = threadIdx.x;
  if (i < NPAIR) out[i] = -dist[i] * (1.0f / HWOUT);
}

// ======================= launch =======================
extern "C" void kernel_launch(void* const* d_in, const int* in_sizes, int n_in,
                              void* d_out, int out_size, void* d_ws, size_t ws_size,
                              hipStream_t stream) {
  (void)in_sizes; (void)n_in; (void)out_size;
  if (ws_size < WS_NEED) return;  // workspace too small: visibly fail rather than corrupt

  const float* img_q = (const float*)d_in[0];
  const float* img_s = (const float*)d_in[1];
  const float* w_qk  = (const float*)d_in[2];
  const float* w_v   = (const float*)d_in[3];
  const float* w_ms  = (const float*)d_in[4];

  char* ws = (char*)d_ws;
  bf16*  Wb   = (bf16*)(ws + OFF_WB);
  bf16*  F    = (bf16*)(ws + OFF_F);
  bf16*  VT   = (bf16*)(ws + OFF_VT);
  float* dist = (float*)(ws + OFF_DIST);
  bf16*  R    = (bf16*)(ws + OFF_R);
  float* S    = (float*)(ws + OFF_R);  // aliases R (R dead after conv)

  hipMemsetAsync(dist, 0, NPAIR * sizeof(float), stream);
  k_wcomb  <<<dim3(72, 4),      256, 0, stream>>>(w_qk, w_v, w_ms, Wb);
  k_repack <<<dim3(27, 8, 208), 256, 0, stream>>>(img_q, img_s, R);
  k_conv   <<<dim3(650),        256, 0, stream>>>(R, Wb, F);
  k_sim    <<<dim3(5, 8, 40),   256, 0, stream>>>(F, S);
  k_vt     <<<dim3(7, 5, 40),   256, 0, stream>>>(F, VT);
  k_out    <<<dim3(13, 40),     256, 0, stream>>>(S, VT, F, dist);
  k_final  <<<1, 64,             0, stream>>>(dist, (float*)d_out);
}